// Round 8
// baseline (780.650 us; speedup 1.0000x reference)
//
#include <hip/hip_runtime.h>

typedef unsigned short u16;
typedef __attribute__((ext_vector_type(8))) short s8v;   // 8 bf16 = 4 VGPRs
typedef __attribute__((ext_vector_type(4))) float f4v;   // MFMA accumulator

__device__ __forceinline__ float bf2f(u16 u) {
    union { unsigned int i; float f; } v;
    v.i = ((unsigned int)u) << 16;
    return v.f;
}
__device__ __forceinline__ u16 f2bf(float f) {
    union { float f; unsigned int i; } v;
    v.f = f;
    unsigned int x = v.i;
    x += 0x7FFFu + ((x >> 16) & 1u);   // round-to-nearest-even
    return (u16)(x >> 16);
}
// dual-dtype scalar load: isf32 ? fp32 : bf16
__device__ __forceinline__ float ldx(const void* p, long long i, int isf) {
    return isf ? ((const float*)p)[i] : bf2f(((const u16*)p)[i]);
}

// Inline dtype probe: 32 samples of even u16 indices of W. bf16 array ->
// plausible exponents ~always; fp32 array -> low-half mantissa bits,
// plausible ~18% => cnt ~6 << 16. Uniform addresses, one cacheline.
__device__ __forceinline__ int probe_isf(const void* W) {
    const u16* p = (const u16*)W;
    int cnt = 0;
#pragma unroll
    for (int i = 0; i < 32; ++i) {
        u16 u = p[2 * i];
        int e = (u >> 7) & 0xFF;
        cnt += ((e == 0) || (e >= 96 && e <= 140)) ? 1 : 0;
    }
    return (cnt < 16) ? 1 : 0;   // 1 = fp32
}

// ---------------------------------------------------------------------------
// Dtype probe kernel (fallback VALU path only).
// ---------------------------------------------------------------------------
__global__ void diag_kernel(const void* W, int* flag) {
    __shared__ int cnt;
    int t = threadIdx.x;
    if (t == 0) cnt = 0;
    __syncthreads();
    u16 u = ((const u16*)W)[2 * t];
    int e = (u >> 7) & 0xFF;
    int plausible = (e == 0) || (e >= 96 && e <= 140);
    atomicAdd(&cnt, plausible);
    __syncthreads();
    if (t == 0) *flag = (cnt < 128) ? 1 : 0;
}

__global__ void magic_kernel(void* out, float code) {
    ((u16*)out)[threadIdx.x] = f2bf(code);
}

// ---------------------------------------------------------------------------
// prep2: zero sums, compute G2e/G2n = globals_ @ {We2_g,Wn2_g}, pack the four
// GEMM weight matrices into MFMA B-fragment order (bf16), publish dtype flag.
//   frag f, lane l, elem j  ->  W[kb*32 + 8*(l>>4) + j][nt*16 + (l&15)]
//   W1 (K=128,N=256): f = kb*16 + nt.   W2 (K=256,N=128): f = kb*8 + nt.
// grid: 576 blocks x 256 = 147456 threads exactly.
// ---------------------------------------------------------------------------
__global__ void prep2_kernel(const void* We2_g, const void* Wn2_g,
                             const void* globals_,
                             const void* We1, const void* Wn1,
                             const void* We2_e, const void* Wn2_n,
                             float* sums_zero, float* G2e, float* G2n,
                             u16* W1e_p, u16* W2e_p, u16* W1n_p, u16* W2n_p,
                             int* flagp)
{
    int isf = probe_isf(We1);
    int t = blockIdx.x * 256 + threadIdx.x;
    if (t == 0) *flagp = isf;          // publish for main/final kernels
    if (t < 65536) { sums_zero[t] = 0.f; return; }
    if (t < 131072) {
        int i = t - 65536;            // 0..65535
        int which = i >> 15;          // 0: G2e, 1: G2n
        int idx = i & 32767;
        int g = idx >> 7, c = idx & 127;
        const void* Wg = which ? Wn2_g : We2_g;
        float s = 0.f;
#pragma unroll 8
        for (int k = 0; k < 64; ++k)
            s += ldx(globals_, g * 64 + k, isf) * ldx(Wg, k * 128 + c, isf);
        if (which) G2n[idx] = s; else G2e[idx] = s;
        return;
    }
    int p = t - 131072;               // 0..16383: weight packing
    int which = p >> 12;              // 0 W1e, 1 W1n, 2 W2e, 3 W2n
    int idx = p & 4095;
    int f = idx >> 6, lj = idx & 63;
    const void* W; u16* dst; int kb, nt, N;
    if (which == 0)      { W = We1;   dst = W1e_p; kb = f >> 4; nt = f & 15; N = 256; }
    else if (which == 1) { W = Wn1;   dst = W1n_p; kb = f >> 4; nt = f & 15; N = 256; }
    else if (which == 2) { W = We2_e; dst = W2e_p; kb = f >> 3; nt = f & 7;  N = 128; }
    else                 { W = Wn2_n; dst = W2n_p; kb = f >> 3; nt = f & 7;  N = 128; }
    int k0 = kb * 32 + 8 * (lj >> 4);
    int n  = nt * 16 + (lj & 15);
    s8v v;
#pragma unroll
    for (int j = 0; j < 8; ++j)
        v[j] = (short)f2bf(ldx(W, (long long)(k0 + j) * N + n, isf));
    *(s8v*)&dst[f * 512 + lj * 8] = v;
}

// ---------------------------------------------------------------------------
// Fused MFMA 2-layer MLP + per-graph row-sum. FOUR 64-row tiles per block
// (R4 body inside a 4-tile loop; per-tile state fully scoped to avoid R3's
// spills — only rs[4]+pointers are loop-carried):
//   blocks [0,1024): edges, 256 rows each, g = bid>>2 (const per block)
//     -> rs accumulated across tiles, ONE atomic flush per block (4-way
//        contention per graph vs R4's 16-way).
//   blocks [1024,1088): nodes, 256 rows each, g = nb*4+t per tile (UNIQUE
//        owner) -> per-tile plain store, zero atomics.
// ---------------------------------------------------------------------------
__global__ __launch_bounds__(256, 4) void QNetwork_89103391522965_kernel(
    const void* edges, const void* nodes,
    const void* be1, const void* bn1, const void* be2, const void* bn2,
    const u16* W1e, const u16* W2e, const u16* W1n, const u16* W2n,
    const float* G2e, const float* G2n,
    float* e_sum, float* n_sum, const int* flagp)
{
    __shared__ u16 E1[64 * 256];      // 32 KB, swizzled addressing
    __shared__ float accb[128];

    const int isf  = *flagp;
    const int tid  = threadIdx.x;
    const int lane = tid & 63;
    const int w    = tid >> 6;
    const int l15  = lane & 15;
    const int lg   = lane >> 4;

    const int bid = blockIdx.x;
    const bool isn = bid >= 1024;
    const int rb = isn ? (bid - 1024) : bid;
    const void* X   = isn ? nodes : edges;
    const void* b1  = isn ? bn1 : be1;
    const void* b2  = isn ? bn2 : be2;
    const u16* W1p  = isn ? W1n : W1e;
    const u16* W2p  = isn ? W2n : W2e;
    const float* gt = isn ? G2n : G2e;
    const int base  = rb * 256;       // first row of this block
    const int ge    = bid >> 2;       // edge graph (const per edge block)

    if (tid < 128) accb[tid] = 0.f;   // visible after first barrier

    const int mb16  = (w >> 1) * 32;  // GEMM2 row base
    const int nbase = (w & 1) * 4;    // GEMM2 col-tile base

    // bias1 per wave (constant across tiles)
    float binit[4];
#pragma unroll
    for (int nj = 0; nj < 4; ++nj)
        binit[nj] = ldx(b1, 64 * w + 16 * nj + l15, isf);

    float rs[4] = {0.f, 0.f, 0.f, 0.f};   // edge row-sum carry (4 VGPR)

    for (int t = 0; t < 4; ++t) {
        const int m0 = base + t * 64;
        const int gg = isn ? (m0 >> 6) : ge;

        // ---- GEMM1: acc[mi][nj], cols 64w + 16nj + l15 (R4 body) ----
        f4v acc1[4][4];
#pragma unroll
        for (int nj = 0; nj < 4; ++nj) {
#pragma unroll
            for (int mi = 0; mi < 4; ++mi) {
                f4v tv = {binit[nj], binit[nj], binit[nj], binit[nj]};
                acc1[mi][nj] = tv;
            }
        }
#pragma unroll
        for (int kb = 0; kb < 4; ++kb) {
            s8v a[4];
            const int k0 = kb * 32 + 8 * lg;
            if (!isf) {
#pragma unroll
                for (int mi = 0; mi < 4; ++mi)
                    a[mi] = *(const s8v*)((const u16*)X +
                             (long long)(m0 + 16 * mi + l15) * 128 + k0);
            } else {
#pragma unroll
                for (int mi = 0; mi < 4; ++mi) {
                    const float* xf = (const float*)X +
                             (long long)(m0 + 16 * mi + l15) * 128 + k0;
                    s8v v;
#pragma unroll
                    for (int j = 0; j < 8; ++j) v[j] = (short)f2bf(xf[j]);
                    a[mi] = v;
                }
            }
#pragma unroll
            for (int nj = 0; nj < 4; ++nj) {
                s8v b = *(const s8v*)&W1p[(kb * 16 + 4 * w + nj) * 512 + lane * 8];
#pragma unroll
                for (int mi = 0; mi < 4; ++mi)
                    acc1[mi][nj] = __builtin_amdgcn_mfma_f32_16x16x32_bf16(
                        a[mi], b, acc1[mi][nj], 0, 0, 0);
            }
        }

        // relu -> E1 (swizzled scatter)
#pragma unroll
        for (int mi = 0; mi < 4; ++mi) {
#pragma unroll
            for (int nj = 0; nj < 4; ++nj) {
                int col = 64 * w + 16 * nj + l15;
#pragma unroll
                for (int r = 0; r < 4; ++r) {
                    int row = 16 * mi + 4 * lg + r;
                    int sw  = ((row ^ (row >> 1)) & 7) << 3;  // u16-idx swizzle
                    E1[(row * 256 + col) ^ sw] = f2bf(fmaxf(acc1[mi][nj][r], 0.f));
                }
            }
        }
        __syncthreads();   // E1 ready; accb init/reset visible

        // ---- GEMM2: wave w -> rows mb16..+31, cols 64*(w&1)..+63 ----
        f4v acc2[2][4];
#pragma unroll
        for (int mp = 0; mp < 2; ++mp)
#pragma unroll
            for (int nj = 0; nj < 4; ++nj) {
                f4v z = {0.f, 0.f, 0.f, 0.f};
                acc2[mp][nj] = z;
            }
#pragma unroll
        for (int kb = 0; kb < 8; ++kb) {
            s8v a2[2];
#pragma unroll
            for (int mp = 0; mp < 2; ++mp) {
                int row = mb16 + mp * 16 + l15;
                int sw  = ((row ^ (row >> 1)) & 7) << 3;
                a2[mp] = *(const s8v*)&E1[(row * 256 + kb * 32 + lg * 8) ^ sw];
            }
#pragma unroll
            for (int nj = 0; nj < 4; ++nj) {
                s8v b = *(const s8v*)&W2p[(kb * 8 + nbase + nj) * 512 + lane * 8];
#pragma unroll
                for (int mp = 0; mp < 2; ++mp)
                    acc2[mp][nj] = __builtin_amdgcn_mfma_f32_16x16x32_bf16(
                        a2[mp], b, acc2[mp][nj], 0, 0, 0);
            }
        }

        // epilogue: +gterm+bias, relu, row-sum
#pragma unroll
        for (int nj = 0; nj < 4; ++nj) {
            int c2 = (nbase + nj) * 16 + l15;
            float add = gt[gg * 128 + c2] + ldx(b2, c2, isf);
            float s = 0.f;
#pragma unroll
            for (int mp = 0; mp < 2; ++mp)
#pragma unroll
                for (int r = 0; r < 4; ++r)
                    s += fmaxf(acc2[mp][nj][r] + add, 0.f);
            if (isn) {
                // per-tile flush (unique graph owner -> plain store)
                s += __shfl_xor(s, 16);
                s += __shfl_xor(s, 32);
                if (lg == 0) atomicAdd(&accb[c2], s);
            } else {
                rs[nj] += s;           // carry across tiles (4 VGPR)
            }
        }
        if (isn) {
            __syncthreads();
            if (tid < 128) {
                n_sum[gg * 128 + tid] = accb[tid];   // no atomics: sole owner
                accb[tid] = 0.f;
            }
        }
        __syncthreads();   // E1 consumed + accb reset visible before next tile
    }

    // edge flush: one per block (4-way contention per graph)
    if (!isn) {
#pragma unroll
        for (int nj = 0; nj < 4; ++nj) {
            float v = rs[nj];
            v += __shfl_xor(v, 16);
            v += __shfl_xor(v, 32);
            if (lg == 0)
                atomicAdd(&accb[(nbase + nj) * 16 + l15], v);
        }
        __syncthreads();
        if (tid < 128)
            atomicAdd(&e_sum[ge * 128 + tid], accb[tid]);
    }
}

// ---------------------------------------------------------------------------
// Old VALU fallback path (used only if workspace is small).
// ---------------------------------------------------------------------------
__global__ void prep_kernel(const void* We2_g, const void* Wn2_g,
                            const void* globals_, const int* flag,
                            float* sums_zero, float* G2e, float* G2n)
{
    int isf = *flag;
    int t = blockIdx.x * 256 + threadIdx.x;
    if (t < 65536) {
        sums_zero[t] = 0.f;
    } else {
        int i = t - 65536;
        int which = i >> 15;
        int idx = i & 32767;
        int g = idx >> 7, c = idx & 127;
        const void* Wg = which ? Wn2_g : We2_g;
        float s = 0.f;
        for (int k = 0; k < 64; ++k)
            s += ldx(globals_, g * 64 + k, isf) * ldx(Wg, k * 128 + c, isf);
        if (which) G2n[idx] = s; else G2e[idx] = s;
    }
}

__global__ void QNetwork_89103391522965_valu(
    const void* X, const void* W1, const void* b1,
    const void* W2, const void* b2, const float* gterm,
    const int* flag, float* sum_out, int rows_per_graph)
{
    __shared__ u16 Xs[64 * 132];
    __shared__ u16 E1[64 * 260];
    __shared__ float accb[128];

    int isf = *flag;
    int tid = threadIdx.x;
    int m0 = blockIdx.x * 64;
    int g = m0 / rows_per_graph;

    if (tid < 128) accb[tid] = 0.f;

    for (int i = 0; i < 32; ++i) {
        int f = tid + i * 256;
        int row = f >> 7, col = f & 127;
        Xs[row * 132 + col] =
            f2bf(ldx(X, (long long)(m0 + row) * 128 + col, isf));
    }
    __syncthreads();

    {
        int c = tid;
        float binit = ldx(b1, c, isf);
        for (int rc = 0; rc < 4; ++rc) {
            float acc[16];
#pragma unroll
            for (int i = 0; i < 16; ++i) acc[i] = binit;
            for (int k = 0; k < 128; k += 2) {
                float w0 = ldx(W1, k * 256 + c, isf);
                float w1 = ldx(W1, (k + 1) * 256 + c, isf);
#pragma unroll
                for (int i = 0; i < 16; ++i) {
                    unsigned int xx =
                        *(const unsigned int*)&Xs[(rc * 16 + i) * 132 + k];
                    acc[i] += bf2f((u16)(xx & 0xFFFFu)) * w0;
                    acc[i] += bf2f((u16)(xx >> 16)) * w1;
                }
            }
#pragma unroll
            for (int i = 0; i < 16; ++i)
                E1[(rc * 16 + i) * 260 + c] = f2bf(fmaxf(acc[i], 0.f));
        }
    }
    __syncthreads();

    {
        int c2 = tid & 127;
        int rh = tid >> 7;
        float add = gterm[g * 128 + c2] + ldx(b2, c2, isf);
        float rowsum = 0.f;
        for (int rc = 0; rc < 2; ++rc) {
            int r0 = rh * 32 + rc * 16;
            float acc[16];
#pragma unroll
            for (int i = 0; i < 16; ++i) acc[i] = 0.f;
            for (int k = 0; k < 256; k += 2) {
                float w0 = ldx(W2, k * 128 + c2, isf);
                float w1 = ldx(W2, (k + 1) * 128 + c2, isf);
#pragma unroll
                for (int i = 0; i < 16; ++i) {
                    unsigned int xx =
                        *(const unsigned int*)&E1[(r0 + i) * 260 + k];
                    acc[i] += bf2f((u16)(xx & 0xFFFFu)) * w0;
                    acc[i] += bf2f((u16)(xx >> 16)) * w1;
                }
            }
#pragma unroll
            for (int i = 0; i < 16; ++i)
                rowsum += fmaxf(acc[i] + add, 0.f);
        }
        atomicAdd(&accb[c2], rowsum);
    }
    __syncthreads();
    if (tid < 128) atomicAdd(&sum_out[g * 128 + tid], accb[tid]);
}

// ---------------------------------------------------------------------------
// Final per-graph head. One block (256 thr) per graph.
// ---------------------------------------------------------------------------
__global__ void final_kernel(
    const float* e_sum, const float* n_sum,
    const void* globals_, const void* a_in,
    const void* Wg_n, const void* Wg_e, const void* Wg_g, const void* bg,
    const void* Wh, const void* bh, const void* Wo, const void* bo,
    const int* flagp, void* out)
{
    __shared__ float navg[128], eavg[128], gv[64], sa[136];
    __shared__ float red[4];
    int isf = *flagp;
    int g = blockIdx.x, t = threadIdx.x;

    if (t < 128) {
        navg[t] = n_sum[g * 128 + t] * (1.f / 64.f);
        eavg[t] = e_sum[g * 128 + t] * (1.f / 1024.f);
    } else if (t < 192) {
        gv[t - 128] = ldx(globals_, g * 64 + (t - 128), isf);
    }
    __syncthreads();

    if (t < 128) {
        float s = ldx(bg, t, isf);
#pragma unroll 8
        for (int k = 0; k < 128; ++k) s += navg[k] * ldx(Wg_n, k * 128 + t, isf);
#pragma unroll 8
        for (int k = 0; k < 128; ++k) s += eavg[k] * ldx(Wg_e, k * 128 + t, isf);
#pragma unroll 8
        for (int k = 0; k < 64;  ++k) s += gv[k]   * ldx(Wg_g, k * 128 + t, isf);
        sa[t] = s;
    } else if (t < 136) {
        sa[t] = ldx(a_in, g * 8 + (t - 128), isf);
    }
    __syncthreads();

    float s = ldx(bh, t, isf);
#pragma unroll 8
    for (int k = 0; k < 136; ++k) s += sa[k] * ldx(Wh, k * 256 + t, isf);
    float hv = fmaxf(s, 0.f) * ldx(Wo, t, isf);
#pragma unroll
    for (int off = 32; off; off >>= 1) hv += __shfl_down(hv, off);
    if ((t & 63) == 0) red[t >> 6] = hv;
    __syncthreads();
    if (t == 0) {
        float val = red[0] + red[1] + red[2] + red[3] + ldx(bo, 0, isf);
        if (isf) ((float*)out)[g] = val;
        else     ((u16*)out)[g]   = f2bf(val);
    }
}

extern "C" void kernel_launch(void* const* d_in, const int* in_sizes, int n_in,
                              void* d_out, int out_size, void* d_ws, size_t ws_size,
                              hipStream_t stream) {
    static const int EXPECT[24] = {
        2097152, 33554432, 16384, 16384, 262144, 2048,
        32768, 256, 32768, 256,
        32768, 8192, 128, 32768, 8192, 128,
        16384, 16384, 8192, 128,
        34816, 256, 256, 1
    };
    float code = 0.f;
    if (n_in != 24) code = 3000.f + n_in;
    else {
        for (int i = 0; i < 24; ++i)
            if (in_sizes[i] != EXPECT[i]) { code = 1000.f + i; break; }
    }
    if (ws_size < 524292 && code == 0.f) code = 4000.f;
    if (code != 0.f) {
        magic_kernel<<<1, 256, 0, stream>>>(d_out, code);
        return;
    }

    const void* nodes    = d_in[0];
    const void* edges    = d_in[1];
    const void* globals_ = d_in[2];
    const void* a_in  = d_in[5];
    const void* We1   = d_in[6];
    const void* be1   = d_in[7];
    const void* Wn1   = d_in[8];
    const void* bn1   = d_in[9];
    const void* We2_e = d_in[10];
    const void* We2_g = d_in[11];
    const void* be2   = d_in[12];
    const void* Wn2_n = d_in[13];
    const void* Wn2_g = d_in[14];
    const void* bn2   = d_in[15];
    const void* Wg_n  = d_in[16];
    const void* Wg_e  = d_in[17];
    const void* Wg_g  = d_in[18];
    const void* bg    = d_in[19];
    const void* Wh    = d_in[20];
    const void* bh    = d_in[21];
    const void* Wo    = d_in[22];
    const void* bo    = d_in[23];

    char* ws = (char*)d_ws;
    float* e_sum = (float*)(ws + 0);        // 131072 B
    float* n_sum = (float*)(ws + 131072);   // 131072 B
    float* G2e   = (float*)(ws + 262144);   // 131072 B
    float* G2n   = (float*)(ws + 393216);   // 131072 B

    if (ws_size >= 786440) {
        // MFMA path: packed weights + flag above the f32 arrays
        u16* W1e_p = (u16*)(ws + 524288);   // 65536 B
        u16* W2e_p = (u16*)(ws + 589824);   // 65536 B
        u16* W1n_p = (u16*)(ws + 655360);   // 65536 B
        u16* W2n_p = (u16*)(ws + 720896);   // 65536 B
        int* flagp = (int*)(ws + 786432);   // 4 B

        prep2_kernel<<<576, 256, 0, stream>>>(We2_g, Wn2_g, globals_,
                                              We1, Wn1, We2_e, Wn2_n,
                                              e_sum, G2e, G2n,
                                              W1e_p, W2e_p, W1n_p, W2n_p,
                                              flagp);
        QNetwork_89103391522965_kernel<<<1088, 256, 0, stream>>>(
            edges, nodes, be1, bn1, be2, bn2,
            W1e_p, W2e_p, W1n_p, W2n_p, G2e, G2n,
            e_sum, n_sum, flagp);
        final_kernel<<<256, 256, 0, stream>>>(e_sum, n_sum, globals_, a_in,
                                              Wg_n, Wg_e, Wg_g, bg, Wh, bh, Wo, bo,
                                              flagp, d_out);
    } else {
        // fallback: original VALU path (workspace too small for packed weights)
        int* flag = (int*)(ws + 524288);
        diag_kernel<<<1, 256, 0, stream>>>(We1, flag);
        prep_kernel<<<512, 256, 0, stream>>>(We2_g, Wn2_g, globals_, flag,
                                             e_sum, G2e, G2n);
        QNetwork_89103391522965_valu<<<4096, 256, 0, stream>>>(
            edges, We1, be1, We2_e, be2, G2e, flag, e_sum, 1024);
        QNetwork_89103391522965_valu<<<256, 256, 0, stream>>>(
            nodes, Wn1, bn1, Wn2_n, bn2, G2n, flag, n_sum, 64);
        final_kernel<<<256, 256, 0, stream>>>(e_sum, n_sum, globals_, a_in,
                                              Wg_n, Wg_e, Wg_g, bg, Wh, bh, Wo, bo,
                                              flag, d_out);
    }
}

// Round 9
// 555.840 us; speedup vs baseline: 1.4045x; 1.4045x over previous
//
#include <hip/hip_runtime.h>

typedef unsigned short u16;
typedef __attribute__((ext_vector_type(8))) short s8v;   // 8 bf16 = 4 VGPRs
typedef __attribute__((ext_vector_type(4))) float f4v;   // MFMA accumulator

__device__ __forceinline__ float bf2f(u16 u) {
    union { unsigned int i; float f; } v;
    v.i = ((unsigned int)u) << 16;
    return v.f;
}
__device__ __forceinline__ u16 f2bf(float f) {
    union { float f; unsigned int i; } v;
    v.f = f;
    unsigned int x = v.i;
    x += 0x7FFFu + ((x >> 16) & 1u);   // round-to-nearest-even
    return (u16)(x >> 16);
}
// dual-dtype scalar load: isf32 ? fp32 : bf16
__device__ __forceinline__ float ldx(const void* p, long long i, int isf) {
    return isf ? ((const float*)p)[i] : bf2f(((const u16*)p)[i]);
}

// Inline dtype probe: 32 samples of even u16 indices of W. bf16 array ->
// plausible exponents ~always; fp32 array -> low-half mantissa bits,
// plausible ~18% => cnt ~6 << 16. Uniform addresses, one cacheline.
__device__ __forceinline__ int probe_isf(const void* W) {
    const u16* p = (const u16*)W;
    int cnt = 0;
#pragma unroll
    for (int i = 0; i < 32; ++i) {
        u16 u = p[2 * i];
        int e = (u >> 7) & 0xFF;
        cnt += ((e == 0) || (e >= 96 && e <= 140)) ? 1 : 0;
    }
    return (cnt < 16) ? 1 : 0;   // 1 = fp32
}

// ---------------------------------------------------------------------------
// Dtype probe kernel (fallback VALU path only).
// ---------------------------------------------------------------------------
__global__ void diag_kernel(const void* W, int* flag) {
    __shared__ int cnt;
    int t = threadIdx.x;
    if (t == 0) cnt = 0;
    __syncthreads();
    u16 u = ((const u16*)W)[2 * t];
    int e = (u >> 7) & 0xFF;
    int plausible = (e == 0) || (e >= 96 && e <= 140);
    atomicAdd(&cnt, plausible);
    __syncthreads();
    if (t == 0) *flag = (cnt < 128) ? 1 : 0;
}

__global__ void magic_kernel(void* out, float code) {
    ((u16*)out)[threadIdx.x] = f2bf(code);
}

// ---------------------------------------------------------------------------
// prep2: zero sums, compute G2e/G2n = globals_ @ {We2_g,Wn2_g}, pack the four
// GEMM weight matrices into MFMA B-fragment order (bf16), publish dtype flag.
//   frag f, lane l, elem j  ->  W[kb*32 + 8*(l>>4) + j][nt*16 + (l&15)]
//   W1 (K=128,N=256): f = kb*16 + nt.   W2 (K=256,N=128): f = kb*8 + nt.
// grid: 576 blocks x 256 = 147456 threads exactly.
// ---------------------------------------------------------------------------
__global__ void prep2_kernel(const void* We2_g, const void* Wn2_g,
                             const void* globals_,
                             const void* We1, const void* Wn1,
                             const void* We2_e, const void* Wn2_n,
                             float* sums_zero, float* G2e, float* G2n,
                             u16* W1e_p, u16* W2e_p, u16* W1n_p, u16* W2n_p,
                             int* flagp)
{
    int isf = probe_isf(We1);
    int t = blockIdx.x * 256 + threadIdx.x;
    if (t == 0) *flagp = isf;          // publish for main/final kernels
    if (t < 65536) { sums_zero[t] = 0.f; return; }
    if (t < 131072) {
        int i = t - 65536;            // 0..65535
        int which = i >> 15;          // 0: G2e, 1: G2n
        int idx = i & 32767;
        int g = idx >> 7, c = idx & 127;
        const void* Wg = which ? Wn2_g : We2_g;
        float s = 0.f;
#pragma unroll 8
        for (int k = 0; k < 64; ++k)
            s += ldx(globals_, g * 64 + k, isf) * ldx(Wg, k * 128 + c, isf);
        if (which) G2n[idx] = s; else G2e[idx] = s;
        return;
    }
    int p = t - 131072;               // 0..16383: weight packing
    int which = p >> 12;              // 0 W1e, 1 W1n, 2 W2e, 3 W2n
    int idx = p & 4095;
    int f = idx >> 6, lj = idx & 63;
    const void* W; u16* dst; int kb, nt, N;
    if (which == 0)      { W = We1;   dst = W1e_p; kb = f >> 4; nt = f & 15; N = 256; }
    else if (which == 1) { W = Wn1;   dst = W1n_p; kb = f >> 4; nt = f & 15; N = 256; }
    else if (which == 2) { W = We2_e; dst = W2e_p; kb = f >> 3; nt = f & 7;  N = 128; }
    else                 { W = Wn2_n; dst = W2n_p; kb = f >> 3; nt = f & 7;  N = 128; }
    int k0 = kb * 32 + 8 * (lj >> 4);
    int n  = nt * 16 + (lj & 15);
    s8v v;
#pragma unroll
    for (int j = 0; j < 8; ++j)
        v[j] = (short)f2bf(ldx(W, (long long)(k0 + j) * N + n, isf));
    *(s8v*)&dst[f * 512 + lj * 8] = v;
}

// ---------------------------------------------------------------------------
// Fused MFMA 2-layer MLP + per-graph row-sum. FOUR 64-row tiles per block.
// ANTI-SPILL design (R8 post-mortem: acc1[4][4]=64 AGPR + loop state spilled
// 256B/tile): GEMM1 runs as FOUR 16-row passes with acc1[4] (16 regs live,
// structure verified spill-free in R5), and the tile/pass loops are forced
// #pragma unroll 1 so the scheduler cannot re-fatten register liveness.
//   blocks [0,1024): edges, 256 rows, g = bid>>2 const -> rs[] carry,
//     ONE atomic flush per block (131K total atomics).
//   blocks [1024,1088): nodes, g unique per tile -> plain stores, 0 atomics.
// ---------------------------------------------------------------------------
__global__ __launch_bounds__(256, 4) void QNetwork_89103391522965_kernel(
    const void* edges, const void* nodes,
    const void* be1, const void* bn1, const void* be2, const void* bn2,
    const u16* W1e, const u16* W2e, const u16* W1n, const u16* W2n,
    const float* G2e, const float* G2n,
    float* e_sum, float* n_sum, const int* flagp)
{
    __shared__ u16 E1[64 * 256];      // 32 KB, swizzled addressing
    __shared__ float accb[128];

    const int isf  = *flagp;
    const int tid  = threadIdx.x;
    const int lane = tid & 63;
    const int w    = tid >> 6;
    const int l15  = lane & 15;
    const int lg   = lane >> 4;

    const int bid = blockIdx.x;
    const bool isn = bid >= 1024;
    const int rb = isn ? (bid - 1024) : bid;
    const void* X   = isn ? nodes : edges;
    const void* b1  = isn ? bn1 : be1;
    const void* b2  = isn ? bn2 : be2;
    const u16* W1p  = isn ? W1n : W1e;
    const u16* W2p  = isn ? W2n : W2e;
    const float* gt = isn ? G2n : G2e;
    const int base  = rb * 256;       // first row of this block
    const int ge    = bid >> 2;       // edge graph (const per edge block)

    if (tid < 128) accb[tid] = 0.f;   // visible after first barrier

    const int mb16  = (w >> 1) * 32;  // GEMM2 row base
    const int nbase = (w & 1) * 4;    // GEMM2 col-tile base

    // bias1 per wave (constant across tiles)
    float binit[4];
#pragma unroll
    for (int nj = 0; nj < 4; ++nj)
        binit[nj] = ldx(b1, 64 * w + 16 * nj + l15, isf);

    float rs[4] = {0.f, 0.f, 0.f, 0.f};   // edge row-sum carry (4 VGPR)

#pragma unroll 1
    for (int t = 0; t < 4; ++t) {
        const int m0 = base + t * 64;
        const int gg = isn ? (m0 >> 6) : ge;

        // ---- GEMM1: four 16-row passes, acc1[4] (16 regs live; R5 form) ----
#pragma unroll 1
        for (int mh = 0; mh < 4; ++mh) {
            f4v acc1[4];
#pragma unroll
            for (int nj = 0; nj < 4; ++nj) {
                f4v tv = {binit[nj], binit[nj], binit[nj], binit[nj]};
                acc1[nj] = tv;
            }
#pragma unroll
            for (int kb = 0; kb < 4; ++kb) {
                const int k0 = kb * 32 + 8 * lg;
                const int row = m0 + 16 * mh + l15;
                s8v a;
                if (!isf) {
                    a = *(const s8v*)((const u16*)X + (long long)row * 128 + k0);
                } else {
                    const float* xf = (const float*)X + (long long)row * 128 + k0;
                    s8v v;
#pragma unroll
                    for (int j = 0; j < 8; ++j) v[j] = (short)f2bf(xf[j]);
                    a = v;
                }
#pragma unroll
                for (int nj = 0; nj < 4; ++nj) {
                    s8v b = *(const s8v*)&W1p[(kb * 16 + 4 * w + nj) * 512 + lane * 8];
                    acc1[nj] = __builtin_amdgcn_mfma_f32_16x16x32_bf16(
                        a, b, acc1[nj], 0, 0, 0);
                }
            }
            // relu -> E1 (swizzled scatter; conflict-free by construction)
#pragma unroll
            for (int nj = 0; nj < 4; ++nj) {
                int col = 64 * w + 16 * nj + l15;
#pragma unroll
                for (int r = 0; r < 4; ++r) {
                    int row = 16 * mh + 4 * lg + r;
                    int sw  = ((row ^ (row >> 1)) & 7) << 3;  // u16-idx swizzle
                    E1[(row * 256 + col) ^ sw] = f2bf(fmaxf(acc1[nj][r], 0.f));
                }
            }
        }
        __syncthreads();   // E1 ready; accb init/reset visible

        // ---- GEMM2: wave w -> rows mb16..+31, cols 64*(w&1)..+63 ----
        f4v acc2[2][4];
#pragma unroll
        for (int mp = 0; mp < 2; ++mp)
#pragma unroll
            for (int nj = 0; nj < 4; ++nj) {
                f4v z = {0.f, 0.f, 0.f, 0.f};
                acc2[mp][nj] = z;
            }
#pragma unroll
        for (int kb = 0; kb < 8; ++kb) {
            s8v a2[2];
#pragma unroll
            for (int mp = 0; mp < 2; ++mp) {
                int row = mb16 + mp * 16 + l15;
                int sw  = ((row ^ (row >> 1)) & 7) << 3;
                a2[mp] = *(const s8v*)&E1[(row * 256 + kb * 32 + lg * 8) ^ sw];
            }
#pragma unroll
            for (int nj = 0; nj < 4; ++nj) {
                s8v b = *(const s8v*)&W2p[(kb * 8 + nbase + nj) * 512 + lane * 8];
#pragma unroll
                for (int mp = 0; mp < 2; ++mp)
                    acc2[mp][nj] = __builtin_amdgcn_mfma_f32_16x16x32_bf16(
                        a2[mp], b, acc2[mp][nj], 0, 0, 0);
            }
        }

        // epilogue: +gterm+bias, relu, row-sum
#pragma unroll
        for (int nj = 0; nj < 4; ++nj) {
            int c2 = (nbase + nj) * 16 + l15;
            float add = gt[gg * 128 + c2] + ldx(b2, c2, isf);
            float s = 0.f;
#pragma unroll
            for (int mp = 0; mp < 2; ++mp)
#pragma unroll
                for (int r = 0; r < 4; ++r)
                    s += fmaxf(acc2[mp][nj][r] + add, 0.f);
            if (isn) {
                s += __shfl_xor(s, 16);
                s += __shfl_xor(s, 32);
                if (lg == 0) atomicAdd(&accb[c2], s);
            } else {
                rs[nj] += s;           // carry across tiles (4 VGPR)
            }
        }
        if (isn) {
            __syncthreads();
            if (tid < 128) {
                n_sum[gg * 128 + tid] = accb[tid];   // sole owner: plain store
                accb[tid] = 0.f;
            }
        }
        __syncthreads();   // E1 consumed + accb reset visible before next tile
    }

    // edge flush: one per block (4-way contention per graph)
    if (!isn) {
#pragma unroll
        for (int nj = 0; nj < 4; ++nj) {
            float v = rs[nj];
            v += __shfl_xor(v, 16);
            v += __shfl_xor(v, 32);
            if (lg == 0)
                atomicAdd(&accb[(nbase + nj) * 16 + l15], v);
        }
        __syncthreads();
        if (tid < 128)
            atomicAdd(&e_sum[ge * 128 + tid], accb[tid]);
    }
}

// ---------------------------------------------------------------------------
// Old VALU fallback path (used only if workspace is small).
// ---------------------------------------------------------------------------
__global__ void prep_kernel(const void* We2_g, const void* Wn2_g,
                            const void* globals_, const int* flag,
                            float* sums_zero, float* G2e, float* G2n)
{
    int isf = *flag;
    int t = blockIdx.x * 256 + threadIdx.x;
    if (t < 65536) {
        sums_zero[t] = 0.f;
    } else {
        int i = t - 65536;
        int which = i >> 15;
        int idx = i & 32767;
        int g = idx >> 7, c = idx & 127;
        const void* Wg = which ? Wn2_g : We2_g;
        float s = 0.f;
        for (int k = 0; k < 64; ++k)
            s += ldx(globals_, g * 64 + k, isf) * ldx(Wg, k * 128 + c, isf);
        if (which) G2n[idx] = s; else G2e[idx] = s;
    }
}

__global__ void QNetwork_89103391522965_valu(
    const void* X, const void* W1, const void* b1,
    const void* W2, const void* b2, const float* gterm,
    const int* flag, float* sum_out, int rows_per_graph)
{
    __shared__ u16 Xs[64 * 132];
    __shared__ u16 E1[64 * 260];
    __shared__ float accb[128];

    int isf = *flag;
    int tid = threadIdx.x;
    int m0 = blockIdx.x * 64;
    int g = m0 / rows_per_graph;

    if (tid < 128) accb[tid] = 0.f;

    for (int i = 0; i < 32; ++i) {
        int f = tid + i * 256;
        int row = f >> 7, col = f & 127;
        Xs[row * 132 + col] =
            f2bf(ldx(X, (long long)(m0 + row) * 128 + col, isf));
    }
    __syncthreads();

    {
        int c = tid;
        float binit = ldx(b1, c, isf);
        for (int rc = 0; rc < 4; ++rc) {
            float acc[16];
#pragma unroll
            for (int i = 0; i < 16; ++i) acc[i] = binit;
            for (int k = 0; k < 128; k += 2) {
                float w0 = ldx(W1, k * 256 + c, isf);
                float w1 = ldx(W1, (k + 1) * 256 + c, isf);
#pragma unroll
                for (int i = 0; i < 16; ++i) {
                    unsigned int xx =
                        *(const unsigned int*)&Xs[(rc * 16 + i) * 132 + k];
                    acc[i] += bf2f((u16)(xx & 0xFFFFu)) * w0;
                    acc[i] += bf2f((u16)(xx >> 16)) * w1;
                }
            }
#pragma unroll
            for (int i = 0; i < 16; ++i)
                E1[(rc * 16 + i) * 260 + c] = f2bf(fmaxf(acc[i], 0.f));
        }
    }
    __syncthreads();

    {
        int c2 = tid & 127;
        int rh = tid >> 7;
        float add = gterm[g * 128 + c2] + ldx(b2, c2, isf);
        float rowsum = 0.f;
        for (int rc = 0; rc < 2; ++rc) {
            int r0 = rh * 32 + rc * 16;
            float acc[16];
#pragma unroll
            for (int i = 0; i < 16; ++i) acc[i] = 0.f;
            for (int k = 0; k < 256; k += 2) {
                float w0 = ldx(W2, k * 128 + c2, isf);
                float w1 = ldx(W2, (k + 1) * 128 + c2, isf);
#pragma unroll
                for (int i = 0; i < 16; ++i) {
                    unsigned int xx =
                        *(const unsigned int*)&E1[(r0 + i) * 260 + k];
                    acc[i] += bf2f((u16)(xx & 0xFFFFu)) * w0;
                    acc[i] += bf2f((u16)(xx >> 16)) * w1;
                }
            }
#pragma unroll
            for (int i = 0; i < 16; ++i)
                rowsum += fmaxf(acc[i] + add, 0.f);
        }
        atomicAdd(&accb[c2], rowsum);
    }
    __syncthreads();
    if (tid < 128) atomicAdd(&sum_out[g * 128 + tid], accb[tid]);
}

// ---------------------------------------------------------------------------
// Final per-graph head. One block (256 thr) per graph.
// ---------------------------------------------------------------------------
__global__ void final_kernel(
    const float* e_sum, const float* n_sum,
    const void* globals_, const void* a_in,
    const void* Wg_n, const void* Wg_e, const void* Wg_g, const void* bg,
    const void* Wh, const void* bh, const void* Wo, const void* bo,
    const int* flagp, void* out)
{
    __shared__ float navg[128], eavg[128], gv[64], sa[136];
    __shared__ float red[4];
    int isf = *flagp;
    int g = blockIdx.x, t = threadIdx.x;

    if (t < 128) {
        navg[t] = n_sum[g * 128 + t] * (1.f / 64.f);
        eavg[t] = e_sum[g * 128 + t] * (1.f / 1024.f);
    } else if (t < 192) {
        gv[t - 128] = ldx(globals_, g * 64 + (t - 128), isf);
    }
    __syncthreads();

    if (t < 128) {
        float s = ldx(bg, t, isf);
#pragma unroll 8
        for (int k = 0; k < 128; ++k) s += navg[k] * ldx(Wg_n, k * 128 + t, isf);
#pragma unroll 8
        for (int k = 0; k < 128; ++k) s += eavg[k] * ldx(Wg_e, k * 128 + t, isf);
#pragma unroll 8
        for (int k = 0; k < 64;  ++k) s += gv[k]   * ldx(Wg_g, k * 128 + t, isf);
        sa[t] = s;
    } else if (t < 136) {
        sa[t] = ldx(a_in, g * 8 + (t - 128), isf);
    }
    __syncthreads();

    float s = ldx(bh, t, isf);
#pragma unroll 8
    for (int k = 0; k < 136; ++k) s += sa[k] * ldx(Wh, k * 256 + t, isf);
    float hv = fmaxf(s, 0.f) * ldx(Wo, t, isf);
#pragma unroll
    for (int off = 32; off; off >>= 1) hv += __shfl_down(hv, off);
    if ((t & 63) == 0) red[t >> 6] = hv;
    __syncthreads();
    if (t == 0) {
        float val = red[0] + red[1] + red[2] + red[3] + ldx(bo, 0, isf);
        if (isf) ((float*)out)[g] = val;
        else     ((u16*)out)[g]   = f2bf(val);
    }
}

extern "C" void kernel_launch(void* const* d_in, const int* in_sizes, int n_in,
                              void* d_out, int out_size, void* d_ws, size_t ws_size,
                              hipStream_t stream) {
    static const int EXPECT[24] = {
        2097152, 33554432, 16384, 16384, 262144, 2048,
        32768, 256, 32768, 256,
        32768, 8192, 128, 32768, 8192, 128,
        16384, 16384, 8192, 128,
        34816, 256, 256, 1
    };
    float code = 0.f;
    if (n_in != 24) code = 3000.f + n_in;
    else {
        for (int i = 0; i < 24; ++i)
            if (in_sizes[i] != EXPECT[i]) { code = 1000.f + i; break; }
    }
    if (ws_size < 524292 && code == 0.f) code = 4000.f;
    if (code != 0.f) {
        magic_kernel<<<1, 256, 0, stream>>>(d_out, code);
        return;
    }

    const void* nodes    = d_in[0];
    const void* edges    = d_in[1];
    const void* globals_ = d_in[2];
    const void* a_in  = d_in[5];
    const void* We1   = d_in[6];
    const void* be1   = d_in[7];
    const void* Wn1   = d_in[8];
    const void* bn1   = d_in[9];
    const void* We2_e = d_in[10];
    const void* We2_g = d_in[11];
    const void* be2   = d_in[12];
    const void* Wn2_n = d_in[13];
    const void* Wn2_g = d_in[14];
    const void* bn2   = d_in[15];
    const void* Wg_n  = d_in[16];
    const void* Wg_e  = d_in[17];
    const void* Wg_g  = d_in[18];
    const void* bg    = d_in[19];
    const void* Wh    = d_in[20];
    const void* bh    = d_in[21];
    const void* Wo    = d_in[22];
    const void* bo    = d_in[23];

    char* ws = (char*)d_ws;
    float* e_sum = (float*)(ws + 0);        // 131072 B
    float* n_sum = (float*)(ws + 131072);   // 131072 B
    float* G2e   = (float*)(ws + 262144);   // 131072 B
    float* G2n   = (float*)(ws + 393216);   // 131072 B

    if (ws_size >= 786440) {
        // MFMA path: packed weights + flag above the f32 arrays
        u16* W1e_p = (u16*)(ws + 524288);   // 65536 B
        u16* W2e_p = (u16*)(ws + 589824);   // 65536 B
        u16* W1n_p = (u16*)(ws + 655360);   // 65536 B
        u16* W2n_p = (u16*)(ws + 720896);   // 65536 B
        int* flagp = (int*)(ws + 786432);   // 4 B

        prep2_kernel<<<576, 256, 0, stream>>>(We2_g, Wn2_g, globals_,
                                              We1, Wn1, We2_e, Wn2_n,
                                              e_sum, G2e, G2n,
                                              W1e_p, W2e_p, W1n_p, W2n_p,
                                              flagp);
        QNetwork_89103391522965_kernel<<<1088, 256, 0, stream>>>(
            edges, nodes, be1, bn1, be2, bn2,
            W1e_p, W2e_p, W1n_p, W2n_p, G2e, G2n,
            e_sum, n_sum, flagp);
        final_kernel<<<256, 256, 0, stream>>>(e_sum, n_sum, globals_, a_in,
                                              Wg_n, Wg_e, Wg_g, bg, Wh, bh, Wo, bo,
                                              flagp, d_out);
    } else {
        // fallback: original VALU path (workspace too small for packed weights)
        int* flag = (int*)(ws + 524288);
        diag_kernel<<<1, 256, 0, stream>>>(We1, flag);
        prep_kernel<<<512, 256, 0, stream>>>(We2_g, Wn2_g, globals_, flag,
                                             e_sum, G2e, G2n);
        QNetwork_89103391522965_valu<<<4096, 256, 0, stream>>>(
            edges, We1, be1, We2_e, be2, G2e, flag, e_sum, 1024);
        QNetwork_89103391522965_valu<<<256, 256, 0, stream>>>(
            nodes, Wn1, bn1, Wn2_n, bn2, G2n, flag, n_sum, 64);
        final_kernel<<<256, 256, 0, stream>>>(e_sum, n_sum, globals_, a_in,
                                              Wg_n, Wg_e, Wg_g, bg, Wh, bh, Wo, bo,
                                              flag, d_out);
    }
}

// Round 10
// 370.301 us; speedup vs baseline: 2.1081x; 1.5010x over previous
//
#include <hip/hip_runtime.h>

typedef unsigned short u16;
typedef __attribute__((ext_vector_type(8))) short s8v;   // 8 bf16 = 4 VGPRs
typedef __attribute__((ext_vector_type(4))) float f4v;   // MFMA accumulator

__device__ __forceinline__ float bf2f(u16 u) {
    union { unsigned int i; float f; } v;
    v.i = ((unsigned int)u) << 16;
    return v.f;
}
__device__ __forceinline__ u16 f2bf(float f) {
    union { float f; unsigned int i; } v;
    v.f = f;
    unsigned int x = v.i;
    x += 0x7FFFu + ((x >> 16) & 1u);   // round-to-nearest-even
    return (u16)(x >> 16);
}
// dual-dtype scalar load: isf32 ? fp32 : bf16
__device__ __forceinline__ float ldx(const void* p, long long i, int isf) {
    return isf ? ((const float*)p)[i] : bf2f(((const u16*)p)[i]);
}

// Inline dtype probe: 32 samples of even u16 indices of W. bf16 array ->
// plausible exponents ~always; fp32 array -> low-half mantissa bits,
// plausible ~18% => cnt ~6 << 16. Uniform addresses, one cacheline.
__device__ __forceinline__ int probe_isf(const void* W) {
    const u16* p = (const u16*)W;
    int cnt = 0;
#pragma unroll
    for (int i = 0; i < 32; ++i) {
        u16 u = p[2 * i];
        int e = (u >> 7) & 0xFF;
        cnt += ((e == 0) || (e >= 96 && e <= 140)) ? 1 : 0;
    }
    return (cnt < 16) ? 1 : 0;   // 1 = fp32
}

// ---------------------------------------------------------------------------
// Dtype probe kernel (fallback VALU path only).
// ---------------------------------------------------------------------------
__global__ void diag_kernel(const void* W, int* flag) {
    __shared__ int cnt;
    int t = threadIdx.x;
    if (t == 0) cnt = 0;
    __syncthreads();
    u16 u = ((const u16*)W)[2 * t];
    int e = (u >> 7) & 0xFF;
    int plausible = (e == 0) || (e >= 96 && e <= 140);
    atomicAdd(&cnt, plausible);
    __syncthreads();
    if (t == 0) *flag = (cnt < 128) ? 1 : 0;
}

__global__ void magic_kernel(void* out, float code) {
    ((u16*)out)[threadIdx.x] = f2bf(code);
}

// ---------------------------------------------------------------------------
// prep2: zero sums, compute G2e/G2n = globals_ @ {We2_g,Wn2_g}, pack the four
// GEMM weight matrices into MFMA B-fragment order (bf16), publish dtype flag.
//   frag f, lane l, elem j  ->  W[kb*32 + 8*(l>>4) + j][nt*16 + (l&15)]
//   W1 (K=128,N=256): f = kb*16 + nt.   W2 (K=256,N=128): f = kb*8 + nt.
// grid: 576 blocks x 256 = 147456 threads exactly.
// ---------------------------------------------------------------------------
__global__ void prep2_kernel(const void* We2_g, const void* Wn2_g,
                             const void* globals_,
                             const void* We1, const void* Wn1,
                             const void* We2_e, const void* Wn2_n,
                             float* sums_zero, float* G2e, float* G2n,
                             u16* W1e_p, u16* W2e_p, u16* W1n_p, u16* W2n_p,
                             int* flagp)
{
    int isf = probe_isf(We1);
    int t = blockIdx.x * 256 + threadIdx.x;
    if (t == 0) *flagp = isf;          // publish for main/final kernels
    if (t < 65536) { sums_zero[t] = 0.f; return; }
    if (t < 131072) {
        int i = t - 65536;            // 0..65535
        int which = i >> 15;          // 0: G2e, 1: G2n
        int idx = i & 32767;
        int g = idx >> 7, c = idx & 127;
        const void* Wg = which ? Wn2_g : We2_g;
        float s = 0.f;
#pragma unroll 8
        for (int k = 0; k < 64; ++k)
            s += ldx(globals_, g * 64 + k, isf) * ldx(Wg, k * 128 + c, isf);
        if (which) G2n[idx] = s; else G2e[idx] = s;
        return;
    }
    int p = t - 131072;               // 0..16383: weight packing
    int which = p >> 12;              // 0 W1e, 1 W1n, 2 W2e, 3 W2n
    int idx = p & 4095;
    int f = idx >> 6, lj = idx & 63;
    const void* W; u16* dst; int kb, nt, N;
    if (which == 0)      { W = We1;   dst = W1e_p; kb = f >> 4; nt = f & 15; N = 256; }
    else if (which == 1) { W = Wn1;   dst = W1n_p; kb = f >> 4; nt = f & 15; N = 256; }
    else if (which == 2) { W = We2_e; dst = W2e_p; kb = f >> 3; nt = f & 7;  N = 128; }
    else                 { W = Wn2_n; dst = W2n_p; kb = f >> 3; nt = f & 7;  N = 128; }
    int k0 = kb * 32 + 8 * (lj >> 4);
    int n  = nt * 16 + (lj & 15);
    s8v v;
#pragma unroll
    for (int j = 0; j < 8; ++j)
        v[j] = (short)f2bf(ldx(W, (long long)(k0 + j) * N + n, isf));
    *(s8v*)&dst[f * 512 + lj * 8] = v;
}

// ---------------------------------------------------------------------------
// Fused MFMA 2-layer MLP + per-graph row-sum. ONE 64-row tile per block
// (R4/R7 proven clean structure — multi-tile abandoned: spills 3/3 tries).
//   blocks [0,4096): edges, g = bid>>4 (16 blocks/graph)
//   blocks [4096,4352): nodes, g = bid-4096 (sole owner -> PLAIN STORE)
// Edge flush: use_part ? bf16 per-block partial store (NO device atomics)
//                      : 128 global atomics per block (R7 path).
// This is the decisive atomic-drain A/B: per-block latency is pinned at
// ~34 us in every clean build; the end-of-block contested atomic flush is
// the last un-removed invariant.
// ---------------------------------------------------------------------------
__global__ __launch_bounds__(256, 4) void QNetwork_89103391522965_kernel(
    const void* edges, const void* nodes,
    const void* be1, const void* bn1, const void* be2, const void* bn2,
    const u16* W1e, const u16* W2e, const u16* W1n, const u16* W2n,
    const float* G2e, const float* G2n,
    float* e_sum, float* n_sum, u16* pe,
    const int* flagp, int use_part)
{
    __shared__ u16 E1[64 * 256];      // 32 KB, swizzled addressing
    __shared__ float accb[128];

    const int isf  = *flagp;
    const int tid  = threadIdx.x;
    const int lane = tid & 63;
    const int w    = tid >> 6;
    const int l15  = lane & 15;
    const int lg   = lane >> 4;

    const int bid = blockIdx.x;
    const bool isn = bid >= 4096;
    const void* X   = isn ? nodes : edges;
    const void* b1  = isn ? bn1 : be1;
    const void* b2  = isn ? bn2 : be2;
    const u16* W1p  = isn ? W1n : W1e;
    const u16* W2p  = isn ? W2n : W2e;
    const float* gt = isn ? G2n : G2e;
    const int m0    = (isn ? (bid - 4096) : bid) * 64;
    const int g     = isn ? (bid - 4096) : (bid >> 4);

    if (tid < 128) accb[tid] = 0.f;   // visible after the E1 barrier

    // ---- GEMM1: acc[mi][nj], cols 64w + 16nj + l15 ----
    f4v acc1[4][4];
#pragma unroll
    for (int nj = 0; nj < 4; ++nj) {
        float bv = ldx(b1, 64 * w + 16 * nj + l15, isf);
#pragma unroll
        for (int mi = 0; mi < 4; ++mi) {
            f4v t = {bv, bv, bv, bv};
            acc1[mi][nj] = t;
        }
    }

#pragma unroll
    for (int kb = 0; kb < 4; ++kb) {
        s8v a[4];
        const int k0 = kb * 32 + 8 * lg;
        if (!isf) {
#pragma unroll
            for (int mi = 0; mi < 4; ++mi)
                a[mi] = *(const s8v*)((const u16*)X +
                         (long long)(m0 + 16 * mi + l15) * 128 + k0);
        } else {
#pragma unroll
            for (int mi = 0; mi < 4; ++mi) {
                const float* xf = (const float*)X +
                         (long long)(m0 + 16 * mi + l15) * 128 + k0;
                s8v v;
#pragma unroll
                for (int j = 0; j < 8; ++j) v[j] = (short)f2bf(xf[j]);
                a[mi] = v;
            }
        }
#pragma unroll
        for (int nj = 0; nj < 4; ++nj) {
            s8v b = *(const s8v*)&W1p[(kb * 16 + 4 * w + nj) * 512 + lane * 8];
#pragma unroll
            for (int mi = 0; mi < 4; ++mi)
                acc1[mi][nj] = __builtin_amdgcn_mfma_f32_16x16x32_bf16(
                    a[mi], b, acc1[mi][nj], 0, 0, 0);
        }
    }

    // relu -> E1 (swizzled scatter)
#pragma unroll
    for (int mi = 0; mi < 4; ++mi) {
#pragma unroll
        for (int nj = 0; nj < 4; ++nj) {
            int col = 64 * w + 16 * nj + l15;
#pragma unroll
            for (int r = 0; r < 4; ++r) {
                int row = 16 * mi + 4 * lg + r;
                int sw  = ((row ^ (row >> 1)) & 7) << 3;   // u16-index swizzle
                E1[(row * 256 + col) ^ sw] = f2bf(fmaxf(acc1[mi][nj][r], 0.f));
            }
        }
    }
    __syncthreads();   // E1 ready; accb init visible

    // ---- GEMM2: wave w -> rows 32*(w>>1)..+31, cols 64*(w&1)..+63 ----
    f4v acc2[2][4];
#pragma unroll
    for (int mp = 0; mp < 2; ++mp)
#pragma unroll
        for (int nj = 0; nj < 4; ++nj) {
            f4v z = {0.f, 0.f, 0.f, 0.f};
            acc2[mp][nj] = z;
        }
    const int mb16  = (w >> 1) * 32;
    const int nbase = (w & 1) * 4;

#pragma unroll
    for (int kb = 0; kb < 8; ++kb) {
        s8v a2[2];
#pragma unroll
        for (int mp = 0; mp < 2; ++mp) {
            int row = mb16 + mp * 16 + l15;
            int sw  = ((row ^ (row >> 1)) & 7) << 3;
            a2[mp] = *(const s8v*)&E1[(row * 256 + kb * 32 + lg * 8) ^ sw];
        }
#pragma unroll
        for (int nj = 0; nj < 4; ++nj) {
            s8v b = *(const s8v*)&W2p[(kb * 8 + nbase + nj) * 512 + lane * 8];
#pragma unroll
            for (int mp = 0; mp < 2; ++mp)
                acc2[mp][nj] = __builtin_amdgcn_mfma_f32_16x16x32_bf16(
                    a2[mp], b, acc2[mp][nj], 0, 0, 0);
        }
    }

    // epilogue: +gterm+bias, relu, row-sum; shfl reduce -> LDS combine
#pragma unroll
    for (int nj = 0; nj < 4; ++nj) {
        int c2 = (nbase + nj) * 16 + l15;
        float add = gt[g * 128 + c2] + ldx(b2, c2, isf);
        float s = 0.f;
#pragma unroll
        for (int mp = 0; mp < 2; ++mp)
#pragma unroll
            for (int r = 0; r < 4; ++r)
                s += fmaxf(acc2[mp][nj][r] + add, 0.f);
        s += __shfl_xor(s, 16);
        s += __shfl_xor(s, 32);
        if (lg == 0)
            atomicAdd(&accb[c2], s);
    }
    __syncthreads();
    if (tid < 128) {
        if (isn) {
            n_sum[g * 128 + tid] = accb[tid];         // sole owner: plain store
        } else if (use_part) {
            pe[(long long)bid * 128 + tid] = f2bf(accb[tid]);  // no atomics
        } else {
            atomicAdd(&e_sum[g * 128 + tid], accb[tid]);       // R7 path
        }
    }
}

// ---------------------------------------------------------------------------
// Old VALU fallback path (used only if workspace is small).
// ---------------------------------------------------------------------------
__global__ void prep_kernel(const void* We2_g, const void* Wn2_g,
                            const void* globals_, const int* flag,
                            float* sums_zero, float* G2e, float* G2n)
{
    int isf = *flag;
    int t = blockIdx.x * 256 + threadIdx.x;
    if (t < 65536) {
        sums_zero[t] = 0.f;
    } else {
        int i = t - 65536;
        int which = i >> 15;
        int idx = i & 32767;
        int g = idx >> 7, c = idx & 127;
        const void* Wg = which ? Wn2_g : We2_g;
        float s = 0.f;
        for (int k = 0; k < 64; ++k)
            s += ldx(globals_, g * 64 + k, isf) * ldx(Wg, k * 128 + c, isf);
        if (which) G2n[idx] = s; else G2e[idx] = s;
    }
}

__global__ void QNetwork_89103391522965_valu(
    const void* X, const void* W1, const void* b1,
    const void* W2, const void* b2, const float* gterm,
    const int* flag, float* sum_out, int rows_per_graph)
{
    __shared__ u16 Xs[64 * 132];
    __shared__ u16 E1[64 * 260];
    __shared__ float accb[128];

    int isf = *flag;
    int tid = threadIdx.x;
    int m0 = blockIdx.x * 64;
    int g = m0 / rows_per_graph;

    if (tid < 128) accb[tid] = 0.f;

    for (int i = 0; i < 32; ++i) {
        int f = tid + i * 256;
        int row = f >> 7, col = f & 127;
        Xs[row * 132 + col] =
            f2bf(ldx(X, (long long)(m0 + row) * 128 + col, isf));
    }
    __syncthreads();

    {
        int c = tid;
        float binit = ldx(b1, c, isf);
        for (int rc = 0; rc < 4; ++rc) {
            float acc[16];
#pragma unroll
            for (int i = 0; i < 16; ++i) acc[i] = binit;
            for (int k = 0; k < 128; k += 2) {
                float w0 = ldx(W1, k * 256 + c, isf);
                float w1 = ldx(W1, (k + 1) * 256 + c, isf);
#pragma unroll
                for (int i = 0; i < 16; ++i) {
                    unsigned int xx =
                        *(const unsigned int*)&Xs[(rc * 16 + i) * 132 + k];
                    acc[i] += bf2f((u16)(xx & 0xFFFFu)) * w0;
                    acc[i] += bf2f((u16)(xx >> 16)) * w1;
                }
            }
#pragma unroll
            for (int i = 0; i < 16; ++i)
                E1[(rc * 16 + i) * 260 + c] = f2bf(fmaxf(acc[i], 0.f));
        }
    }
    __syncthreads();

    {
        int c2 = tid & 127;
        int rh = tid >> 7;
        float add = gterm[g * 128 + c2] + ldx(b2, c2, isf);
        float rowsum = 0.f;
        for (int rc = 0; rc < 2; ++rc) {
            int r0 = rh * 32 + rc * 16;
            float acc[16];
#pragma unroll
            for (int i = 0; i < 16; ++i) acc[i] = 0.f;
            for (int k = 0; k < 256; k += 2) {
                float w0 = ldx(W2, k * 128 + c2, isf);
                float w1 = ldx(W2, (k + 1) * 128 + c2, isf);
#pragma unroll
                for (int i = 0; i < 16; ++i) {
                    unsigned int xx =
                        *(const unsigned int*)&E1[(r0 + i) * 260 + k];
                    acc[i] += bf2f((u16)(xx & 0xFFFFu)) * w0;
                    acc[i] += bf2f((u16)(xx >> 16)) * w1;
                }
            }
#pragma unroll
            for (int i = 0; i < 16; ++i)
                rowsum += fmaxf(acc[i] + add, 0.f);
        }
        atomicAdd(&accb[c2], rowsum);
    }
    __syncthreads();
    if (tid < 128) atomicAdd(&sum_out[g * 128 + tid], accb[tid]);
}

// ---------------------------------------------------------------------------
// Final per-graph head. One block (256 thr) per graph.
// use_part: sum the 16 bf16 edge partials; else read atomic e_sum.
// n_sum is plain-stored by the MFMA path (sole owner) or atomics (fallback).
// ---------------------------------------------------------------------------
__global__ void final_kernel(
    const float* e_sum, const float* n_sum, const u16* pe,
    const void* globals_, const void* a_in,
    const void* Wg_n, const void* Wg_e, const void* Wg_g, const void* bg,
    const void* Wh, const void* bh, const void* Wo, const void* bo,
    const int* flagp, int use_part, void* out)
{
    __shared__ float navg[128], eavg[128], gv[64], sa[136];
    __shared__ float red[4];
    int isf = *flagp;
    int g = blockIdx.x, t = threadIdx.x;

    if (t < 128) {
        float es;
        if (use_part) {
            const u16* p = pe + (long long)(g * 16) * 128 + t;
            float s = 0.f;
#pragma unroll
            for (int j = 0; j < 16; ++j) s += bf2f(p[j * 128]);
            es = s;
        } else {
            es = e_sum[g * 128 + t];
        }
        navg[t] = n_sum[g * 128 + t] * (1.f / 64.f);
        eavg[t] = es * (1.f / 1024.f);
    } else if (t < 192) {
        gv[t - 128] = ldx(globals_, g * 64 + (t - 128), isf);
    }
    __syncthreads();

    if (t < 128) {
        float s = ldx(bg, t, isf);
#pragma unroll 8
        for (int k = 0; k < 128; ++k) s += navg[k] * ldx(Wg_n, k * 128 + t, isf);
#pragma unroll 8
        for (int k = 0; k < 128; ++k) s += eavg[k] * ldx(Wg_e, k * 128 + t, isf);
#pragma unroll 8
        for (int k = 0; k < 64;  ++k) s += gv[k]   * ldx(Wg_g, k * 128 + t, isf);
        sa[t] = s;
    } else if (t < 136) {
        sa[t] = ldx(a_in, g * 8 + (t - 128), isf);
    }
    __syncthreads();

    float s = ldx(bh, t, isf);
#pragma unroll 8
    for (int k = 0; k < 136; ++k) s += sa[k] * ldx(Wh, k * 256 + t, isf);
    float hv = fmaxf(s, 0.f) * ldx(Wo, t, isf);
#pragma unroll
    for (int off = 32; off; off >>= 1) hv += __shfl_down(hv, off);
    if ((t & 63) == 0) red[t >> 6] = hv;
    __syncthreads();
    if (t == 0) {
        float val = red[0] + red[1] + red[2] + red[3] + ldx(bo, 0, isf);
        if (isf) ((float*)out)[g] = val;
        else     ((u16*)out)[g]   = f2bf(val);
    }
}

extern "C" void kernel_launch(void* const* d_in, const int* in_sizes, int n_in,
                              void* d_out, int out_size, void* d_ws, size_t ws_size,
                              hipStream_t stream) {
    static const int EXPECT[24] = {
        2097152, 33554432, 16384, 16384, 262144, 2048,
        32768, 256, 32768, 256,
        32768, 8192, 128, 32768, 8192, 128,
        16384, 16384, 8192, 128,
        34816, 256, 256, 1
    };
    float code = 0.f;
    if (n_in != 24) code = 3000.f + n_in;
    else {
        for (int i = 0; i < 24; ++i)
            if (in_sizes[i] != EXPECT[i]) { code = 1000.f + i; break; }
    }
    if (ws_size < 524292 && code == 0.f) code = 4000.f;
    if (code != 0.f) {
        magic_kernel<<<1, 256, 0, stream>>>(d_out, code);
        return;
    }

    const void* nodes    = d_in[0];
    const void* edges    = d_in[1];
    const void* globals_ = d_in[2];
    const void* a_in  = d_in[5];
    const void* We1   = d_in[6];
    const void* be1   = d_in[7];
    const void* Wn1   = d_in[8];
    const void* bn1   = d_in[9];
    const void* We2_e = d_in[10];
    const void* We2_g = d_in[11];
    const void* be2   = d_in[12];
    const void* Wn2_n = d_in[13];
    const void* Wn2_g = d_in[14];
    const void* bn2   = d_in[15];
    const void* Wg_n  = d_in[16];
    const void* Wg_e  = d_in[17];
    const void* Wg_g  = d_in[18];
    const void* bg    = d_in[19];
    const void* Wh    = d_in[20];
    const void* bh    = d_in[21];
    const void* Wo    = d_in[22];
    const void* bo    = d_in[23];

    char* ws = (char*)d_ws;
    float* e_sum = (float*)(ws + 0);        // 131072 B
    float* n_sum = (float*)(ws + 131072);   // 131072 B
    float* G2e   = (float*)(ws + 262144);   // 131072 B
    float* G2n   = (float*)(ws + 393216);   // 131072 B

    if (ws_size >= 786440) {
        // MFMA path: packed weights + flag above the f32 arrays
        u16* W1e_p = (u16*)(ws + 524288);   // 65536 B
        u16* W2e_p = (u16*)(ws + 589824);   // 65536 B
        u16* W1n_p = (u16*)(ws + 655360);   // 65536 B
        u16* W2n_p = (u16*)(ws + 720896);   // 65536 B
        int* flagp = (int*)(ws + 786432);   // 4 B (pad to 787456)

        // bf16 edge-partial tier: pe = 4096 blocks x 128 bf16 = 1 MB
        u16* pe = (u16*)(ws + 787456);
        const int use_part =
            (ws_size >= (size_t)(787456 + 1048576)) ? 1 : 0;   // 1,836,032

        prep2_kernel<<<576, 256, 0, stream>>>(We2_g, Wn2_g, globals_,
                                              We1, Wn1, We2_e, Wn2_n,
                                              e_sum, G2e, G2n,
                                              W1e_p, W2e_p, W1n_p, W2n_p,
                                              flagp);
        QNetwork_89103391522965_kernel<<<4352, 256, 0, stream>>>(
            edges, nodes, be1, bn1, be2, bn2,
            W1e_p, W2e_p, W1n_p, W2n_p, G2e, G2n,
            e_sum, n_sum, pe, flagp, use_part);
        final_kernel<<<256, 256, 0, stream>>>(e_sum, n_sum, pe,
                                              globals_, a_in,
                                              Wg_n, Wg_e, Wg_g, bg, Wh, bh, Wo, bo,
                                              flagp, use_part, d_out);
    } else {
        // fallback: original VALU path (workspace too small for packed weights)
        int* flag = (int*)(ws + 524288);
        diag_kernel<<<1, 256, 0, stream>>>(We1, flag);
        prep_kernel<<<512, 256, 0, stream>>>(We2_g, Wn2_g, globals_, flag,
                                             e_sum, G2e, G2n);
        QNetwork_89103391522965_valu<<<4096, 256, 0, stream>>>(
            edges, We1, be1, We2_e, be2, G2e, flag, e_sum, 1024);
        QNetwork_89103391522965_valu<<<256, 256, 0, stream>>>(
            nodes, Wn1, bn1, Wn2_n, bn2, G2n, flag, n_sum, 64);
        final_kernel<<<256, 256, 0, stream>>>(e_sum, n_sum, (const u16*)e_sum,
                                              globals_, a_in,
                                              Wg_n, Wg_e, Wg_g, bg, Wh, bh, Wo, bo,
                                              flag, 0, d_out);
    }
}